// Round 1
// baseline (768.734 us; speedup 1.0000x reference)
//
#include <hip/hip_runtime.h>
#include <hip/hip_bf16.h>

#define H 1024
#define I_DIM 704
#define E 32
#define G_GRP 8
#define TOPK_GROUP 3
#define K_TOP 6
#define T_TOK 2048
#define CAP 768
#define IS_DIM 1408   // N_SHARED * I

#define BM 64
#define BN 64
#define BK 32
#define LDP 40        // padded LDS row stride (shorts): 32 + 8, keeps 16B alignment, 2-way banks

typedef __attribute__((ext_vector_type(8))) short short8v;
typedef __attribute__((ext_vector_type(4))) float f32x4;

__device__ __forceinline__ unsigned short f2bfbits(float f) {
  unsigned u = __float_as_uint(f);
  unsigned r = (u + 0x7fffu + ((u >> 16) & 1u)) >> 16;  // RTNE
  return (unsigned short)r;
}
__device__ __forceinline__ unsigned packbf2(float lo, float hi) {
  return (unsigned)f2bfbits(lo) | ((unsigned)f2bfbits(hi) << 16);
}

// ---------------- cast x (fp32) -> bf16 bits ----------------
__global__ void cast_x_kernel(const float* __restrict__ x, short* __restrict__ xb) {
  size_t i = ((size_t)blockIdx.x * 256 + threadIdx.x) * 4;
  float4 v = *(const float4*)(x + i);
  short4 s;
  s.x = (short)f2bfbits(v.x); s.y = (short)f2bfbits(v.y);
  s.z = (short)f2bfbits(v.z); s.w = (short)f2bfbits(v.w);
  *(short4*)(xb + i) = s;
}

// ---------------- gating: fp64 logits + softmax + group top-3 + top-6 ----------------
__global__ __launch_bounds__(64) void gating_kernel(const float* __restrict__ x,
                                                    const float* __restrict__ gw,
                                                    int* __restrict__ tidx,
                                                    float* __restrict__ tw) {
  int t = blockIdx.x;
  int lane = threadIdx.x;
  int e = lane & 31, half = lane >> 5;
  const float* xr = x + (size_t)t * H;
  const float* wr = gw + (size_t)e * H;
  double acc = 0.0;
  int base = half * 512;
  #pragma unroll 8
  for (int j = 0; j < 512; ++j) acc += (double)xr[base + j] * (double)wr[base + j];
  acc += __shfl_down(acc, 32);
  __shared__ double sc[32];
  if (lane < 32) sc[lane] = acc;
  __syncthreads();
  if (lane == 0) {
    double lg[32], p[32];
    double m = -1e300;
    for (int i = 0; i < 32; ++i) { lg[i] = sc[i]; if (lg[i] > m) m = lg[i]; }
    double sum = 0.0;
    for (int i = 0; i < 32; ++i) { p[i] = exp(lg[i] - m); sum += p[i]; }
    for (int i = 0; i < 32; ++i) p[i] /= sum;
    // group scores = max of 4
    double gs[8];
    for (int g = 0; g < 8; ++g) {
      double mm = p[4 * g];
      for (int j = 1; j < 4; ++j) if (p[4 * g + j] > mm) mm = p[4 * g + j];
      gs[g] = mm;
    }
    // top-3 groups (strict > => lowest index on tie, matches lax.top_k)
    bool gsel[8] = {false,false,false,false,false,false,false,false};
    for (int it = 0; it < TOPK_GROUP; ++it) {
      int best = -1; double bv = -1e300;
      for (int g = 0; g < 8; ++g) if (!gsel[g] && gs[g] > bv) { bv = gs[g]; best = g; }
      gsel[best] = true;
    }
    double mp[32];
    for (int i = 0; i < 32; ++i) mp[i] = gsel[i >> 2] ? p[i] : 0.0;
    for (int it = 0; it < K_TOP; ++it) {
      int best = -1; double bv = -1e300;
      for (int i = 0; i < 32; ++i) if (mp[i] > bv) { bv = mp[i]; best = i; }
      tidx[t * K_TOP + it] = best;
      tw[t * K_TOP + it] = (float)bv;  // SCALE = 1.0
      mp[best] = -2.0;
    }
  }
}

// ---------------- dispatch: stable flat-order compaction per expert ----------------
__global__ __launch_bounds__(64) void dispatch_kernel(const int* __restrict__ tidx,
                                                      const float* __restrict__ tw,
                                                      int* __restrict__ token_list,
                                                      float* __restrict__ slot_w,
                                                      int* __restrict__ cnt) {
  int e = blockIdx.x;
  int lane = threadIdx.x;
  int base = 0;
  for (int c = 0; c < T_TOK * K_TOP; c += 64) {
    int idx = c + lane;
    int te = tidx[idx];
    bool m = (te == e);
    unsigned long long bal = __ballot(m);
    if (m) {
      int pos = base + __popcll(bal & ((1ull << lane) - 1ull));
      if (pos < CAP) {
        token_list[e * CAP + pos] = idx / K_TOP;
        slot_w[e * CAP + pos] = tw[idx];
      }
    }
    base += __popcll(bal);
  }
  if (lane == 0) cnt[e] = base < CAP ? base : CAP;
}

// ---------------- fused gate+up GEMM -> S = silu(g)*u (bf16) ----------------
// A: bf16 x rows (gathered via token_list, or direct). B: fp32 weights (H x N, n-contig),
// transposed to LDS [n][k] during staging. 64x64 tile, 4 waves 2x2, 16x16x32 MFMA.
__global__ __launch_bounds__(256) void gateup_kernel(
    const short* __restrict__ Xb, const float* __restrict__ Wg, const float* __restrict__ Wu,
    short* __restrict__ Sout, const int* __restrict__ tlist, const int* __restrict__ cnt_dev,
    int ldb, int ldS, long long wstride, long long sstride) {
  int e = blockIdx.z;
  int cnt = cnt_dev ? cnt_dev[e] : T_TOK;
  int row0 = blockIdx.y * BM;
  if (row0 >= cnt) return;
  int col0 = blockIdx.x * BN;
  const float* wg = Wg + (long long)e * wstride;
  const float* wu = Wu + (long long)e * wstride;
  short* sbase = Sout + (long long)e * sstride;
  const int* tl = tlist ? tlist + e * CAP : nullptr;

  int tid = threadIdx.x;
  int lane = tid & 63;
  int wave = tid >> 6;
  int wm = wave & 1, wn = wave >> 1;

  __shared__ __align__(16) short As[BM * LDP];
  __shared__ __align__(16) short Bg[BN * LDP];
  __shared__ __align__(16) short Bu[BN * LDP];

  // A staging: row = tid>>2 (64), k-chunk = (tid&3)*8
  int ar = tid >> 2, acg = tid & 3;
  int arow = row0 + ar;
  const short* aptr = Xb;
  bool aok;
  if (tl) { int tok = (arow < cnt) ? tl[arow] : -1; aok = (tok >= 0);
            if (aok) aptr = Xb + (size_t)tok * H + acg * 8; }
  else    { aok = true; aptr = Xb + (size_t)arow * H + acg * 8; }

  // B staging: k-pair = tid&15 (k=2kp,2kp+1), n-group = tid>>4 (n=4ng..+3)
  int kp = tid & 15, ng = tid >> 4;
  const float* bgp = wg + (size_t)(2 * kp) * ldb + col0 + 4 * ng;
  const float* bup = wu + (size_t)(2 * kp) * ldb + col0 + 4 * ng;

  f32x4 accg[2][2], accu[2][2];
  for (int i = 0; i < 2; ++i) for (int j = 0; j < 2; ++j) {
    accg[i][j] = (f32x4){0.f,0.f,0.f,0.f}; accu[i][j] = (f32x4){0.f,0.f,0.f,0.f};
  }

  for (int k0 = 0; k0 < H; k0 += BK) {
    short8v av = {0,0,0,0,0,0,0,0};
    if (aok) av = *(const short8v*)(aptr + k0);
    const float* bg0 = bgp + (size_t)k0 * ldb;
    float4 g0 = *(const float4*)(bg0);
    float4 g1 = *(const float4*)(bg0 + ldb);
    const float* bu0 = bup + (size_t)k0 * ldb;
    float4 u0 = *(const float4*)(bu0);
    float4 u1 = *(const float4*)(bu0 + ldb);
    __syncthreads();
    *(short8v*)&As[ar * LDP + acg * 8] = av;
    *(unsigned*)&Bg[(4 * ng + 0) * LDP + 2 * kp] = packbf2(g0.x, g1.x);
    *(unsigned*)&Bg[(4 * ng + 1) * LDP + 2 * kp] = packbf2(g0.y, g1.y);
    *(unsigned*)&Bg[(4 * ng + 2) * LDP + 2 * kp] = packbf2(g0.z, g1.z);
    *(unsigned*)&Bg[(4 * ng + 3) * LDP + 2 * kp] = packbf2(g0.w, g1.w);
    *(unsigned*)&Bu[(4 * ng + 0) * LDP + 2 * kp] = packbf2(u0.x, u1.x);
    *(unsigned*)&Bu[(4 * ng + 1) * LDP + 2 * kp] = packbf2(u0.y, u1.y);
    *(unsigned*)&Bu[(4 * ng + 2) * LDP + 2 * kp] = packbf2(u0.z, u1.z);
    *(unsigned*)&Bu[(4 * ng + 3) * LDP + 2 * kp] = packbf2(u0.w, u1.w);
    __syncthreads();
    int q = lane >> 4, c = lane & 15;
    short8v a[2], bg[2], bu[2];
    #pragma unroll
    for (int mi = 0; mi < 2; ++mi)
      a[mi] = *(const short8v*)&As[(wm * 32 + mi * 16 + c) * LDP + q * 8];
    #pragma unroll
    for (int ni = 0; ni < 2; ++ni) {
      bg[ni] = *(const short8v*)&Bg[(wn * 32 + ni * 16 + c) * LDP + q * 8];
      bu[ni] = *(const short8v*)&Bu[(wn * 32 + ni * 16 + c) * LDP + q * 8];
    }
    #pragma unroll
    for (int mi = 0; mi < 2; ++mi)
      #pragma unroll
      for (int ni = 0; ni < 2; ++ni) {
        accg[mi][ni] = __builtin_amdgcn_mfma_f32_16x16x32_bf16(a[mi], bg[ni], accg[mi][ni], 0, 0, 0);
        accu[mi][ni] = __builtin_amdgcn_mfma_f32_16x16x32_bf16(a[mi], bu[ni], accu[mi][ni], 0, 0, 0);
      }
  }
  // epilogue: S = silu(g)*u  (C/D: row = quad*4+reg, col = lane&15)
  int q = lane >> 4, c = lane & 15;
  #pragma unroll
  for (int mi = 0; mi < 2; ++mi) {
    int rbase = row0 + wm * 32 + mi * 16 + q * 4;
    #pragma unroll
    for (int ni = 0; ni < 2; ++ni) {
      int col = col0 + wn * 32 + ni * 16 + c;
      #pragma unroll
      for (int r = 0; r < 4; ++r) {
        float g = accg[mi][ni][r], u = accu[mi][ni][r];
        float s = (g / (1.f + __expf(-g))) * u;
        sbase[(size_t)(rbase + r) * ldS + col] = (short)f2bfbits(s);
      }
    }
  }
}

// ---------------- down GEMM: Y = S @ Wd; epilogue scatter-add (routed) or store (shared) ----------------
__global__ __launch_bounds__(256) void down_kernel(
    const short* __restrict__ Sin, const float* __restrict__ Wd, float* __restrict__ out,
    const int* __restrict__ tlist, const float* __restrict__ slot_w, const int* __restrict__ cnt_dev,
    int Kdim, int lda, long long wstride, long long sstride) {
  int e = blockIdx.z;
  int cnt = cnt_dev ? cnt_dev[e] : T_TOK;
  int row0 = blockIdx.y * BM;
  if (row0 >= cnt) return;
  int col0 = blockIdx.x * BN;
  const float* wd = Wd + (long long)e * wstride;
  const short* sb = Sin + (long long)e * sstride;
  const int* tl = tlist ? tlist + e * CAP : nullptr;
  const float* swt = tlist ? slot_w + e * CAP : nullptr;

  int tid = threadIdx.x;
  int lane = tid & 63;
  int wave = tid >> 6;
  int wm = wave & 1, wn = wave >> 1;

  __shared__ __align__(16) short As[BM * LDP];
  __shared__ __align__(16) short Bs[BN * LDP];

  int ar = tid >> 2, acg = tid & 3;
  const short* aptr = sb + (size_t)(row0 + ar) * lda + acg * 8;
  int kp = tid & 15, ng = tid >> 4;
  const float* bp = wd + (size_t)(2 * kp) * H + col0 + 4 * ng;

  f32x4 acc[2][2];
  for (int i = 0; i < 2; ++i) for (int j = 0; j < 2; ++j) acc[i][j] = (f32x4){0.f,0.f,0.f,0.f};

  for (int k0 = 0; k0 < Kdim; k0 += BK) {
    short8v av = *(const short8v*)(aptr + k0);
    const float* b0 = bp + (size_t)k0 * H;
    float4 w0 = *(const float4*)(b0);
    float4 w1 = *(const float4*)(b0 + H);
    __syncthreads();
    *(short8v*)&As[ar * LDP + acg * 8] = av;
    *(unsigned*)&Bs[(4 * ng + 0) * LDP + 2 * kp] = packbf2(w0.x, w1.x);
    *(unsigned*)&Bs[(4 * ng + 1) * LDP + 2 * kp] = packbf2(w0.y, w1.y);
    *(unsigned*)&Bs[(4 * ng + 2) * LDP + 2 * kp] = packbf2(w0.z, w1.z);
    *(unsigned*)&Bs[(4 * ng + 3) * LDP + 2 * kp] = packbf2(w0.w, w1.w);
    __syncthreads();
    int q = lane >> 4, c = lane & 15;
    short8v a[2], b[2];
    #pragma unroll
    for (int mi = 0; mi < 2; ++mi)
      a[mi] = *(const short8v*)&As[(wm * 32 + mi * 16 + c) * LDP + q * 8];
    #pragma unroll
    for (int ni = 0; ni < 2; ++ni)
      b[ni] = *(const short8v*)&Bs[(wn * 32 + ni * 16 + c) * LDP + q * 8];
    #pragma unroll
    for (int mi = 0; mi < 2; ++mi)
      #pragma unroll
      for (int ni = 0; ni < 2; ++ni)
        acc[mi][ni] = __builtin_amdgcn_mfma_f32_16x16x32_bf16(a[mi], b[ni], acc[mi][ni], 0, 0, 0);
  }
  int q = lane >> 4, c = lane & 15;
  if (tl) {
    #pragma unroll
    for (int mi = 0; mi < 2; ++mi) {
      int rb = row0 + wm * 32 + mi * 16 + q * 4;
      #pragma unroll
      for (int r = 0; r < 4; ++r) {
        int s = rb + r;
        if (s < cnt) {
          int tkn = tl[s];
          float w = swt[s];
          #pragma unroll
          for (int ni = 0; ni < 2; ++ni) {
            int col = col0 + wn * 32 + ni * 16 + c;
            atomicAdd(&out[(size_t)tkn * H + col], w * acc[mi][ni][r]);
          }
        }
      }
    }
  } else {
    #pragma unroll
    for (int mi = 0; mi < 2; ++mi) {
      int rb = row0 + wm * 32 + mi * 16 + q * 4;
      #pragma unroll
      for (int ni = 0; ni < 2; ++ni) {
        int col = col0 + wn * 32 + ni * 16 + c;
        #pragma unroll
        for (int r = 0; r < 4; ++r)
          out[(size_t)(rb + r) * H + col] = acc[mi][ni][r];
      }
    }
  }
}

extern "C" void kernel_launch(void* const* d_in, const int* in_sizes, int n_in,
                              void* d_out, int out_size, void* d_ws, size_t ws_size,
                              hipStream_t stream) {
  const float* x       = (const float*)d_in[0];
  const float* gate_w  = (const float*)d_in[1];
  const float* w_gate  = (const float*)d_in[2];
  const float* w_up    = (const float*)d_in[3];
  const float* w_down  = (const float*)d_in[4];
  const float* sw_gate = (const float*)d_in[5];
  const float* sw_up   = (const float*)d_in[6];
  const float* sw_down = (const float*)d_in[7];
  float* out = (float*)d_out;
  char* ws = (char*)d_ws;

  size_t o = 0;
  short* xb = (short*)(ws + o);        o += (size_t)T_TOK * H * 2;          // 4 MB
  short* Sr = (short*)(ws + o);        o += (size_t)E * CAP * I_DIM * 2;    // 33 MB
  short* Ss = (short*)(ws + o);        o += (size_t)T_TOK * IS_DIM * 2;     // 5.5 MB
  int*   tidx = (int*)(ws + o);        o += (size_t)T_TOK * K_TOP * 4;
  float* twt  = (float*)(ws + o);      o += (size_t)T_TOK * K_TOP * 4;
  int*   tl   = (int*)(ws + o);        o += (size_t)E * CAP * 4;
  float* swt  = (float*)(ws + o);      o += (size_t)E * CAP * 4;
  int*   cnt  = (int*)(ws + o);        o += 256;

  cast_x_kernel<<<(T_TOK * H) / 1024, 256, 0, stream>>>(x, xb);
  gating_kernel<<<T_TOK, 64, 0, stream>>>(x, gate_w, tidx, twt);
  dispatch_kernel<<<E, 64, 0, stream>>>(tidx, twt, tl, swt, cnt);
  // routed gate+up -> Sr
  gateup_kernel<<<dim3(I_DIM / BN, CAP / BM, E), 256, 0, stream>>>(
      xb, w_gate, w_up, Sr, tl, cnt, I_DIM, I_DIM, (long long)H * I_DIM, (long long)CAP * I_DIM);
  // shared gate+up -> Ss
  gateup_kernel<<<dim3(IS_DIM / BN, T_TOK / BM, 1), 256, 0, stream>>>(
      xb, sw_gate, sw_up, Ss, nullptr, nullptr, IS_DIM, IS_DIM, 0, 0);
  // shared down: writes out (full init)
  down_kernel<<<dim3(H / BN, T_TOK / BM, 1), 256, 0, stream>>>(
      Ss, sw_down, out, nullptr, nullptr, nullptr, IS_DIM, IS_DIM, 0, 0);
  // routed down: atomic scatter-add into out (after shared init)
  down_kernel<<<dim3(H / BN, CAP / BM, E), 256, 0, stream>>>(
      Sr, w_down, out, tl, swt, cnt, I_DIM, I_DIM, (long long)I_DIM * H, (long long)CAP * I_DIM);
}

// Round 2
// 664.233 us; speedup vs baseline: 1.1573x; 1.1573x over previous
//
#include <hip/hip_runtime.h>
#include <hip/hip_bf16.h>

#define H 1024
#define I_DIM 704
#define E 32
#define TOPK_GROUP 3
#define K_TOP 6
#define T_TOK 2048
#define CAP 768
#define IS_DIM 1408   // N_SHARED * I

typedef __attribute__((ext_vector_type(8))) short short8v;
typedef __attribute__((ext_vector_type(4))) float f32x4;

__device__ __forceinline__ unsigned short f2bfbits(float f) {
  unsigned u = __float_as_uint(f);
  unsigned r = (u + 0x7fffu + ((u >> 16) & 1u)) >> 16;  // RTNE
  return (unsigned short)r;
}
__device__ __forceinline__ unsigned packbf2(float lo, float hi) {
  return (unsigned)f2bfbits(lo) | ((unsigned)f2bfbits(hi) << 16);
}
__device__ __forceinline__ void gload_lds16(const short* g, short* l) {
  __builtin_amdgcn_global_load_lds(
      (const __attribute__((address_space(1))) unsigned int*)g,
      (__attribute__((address_space(3))) unsigned int*)l, 16, 0, 0);
}

// ---------------- cast x (fp32) -> bf16 bits ----------------
__global__ void cast_x_kernel(const float* __restrict__ x, short* __restrict__ xb) {
  size_t i = ((size_t)blockIdx.x * 256 + threadIdx.x) * 4;
  float4 v = *(const float4*)(x + i);
  short4 s;
  s.x = (short)f2bfbits(v.x); s.y = (short)f2bfbits(v.y);
  s.z = (short)f2bfbits(v.z); s.w = (short)f2bfbits(v.w);
  *(short4*)(xb + i) = s;
}

// ---------------- transpose + cast: in [C][N] fp32 -> out [N][C] bf16 ----------------
// 64x64 tile per block, 256 threads.
__global__ __launch_bounds__(256) void transpose_cast_kernel(
    const float* __restrict__ in, short* __restrict__ outp,
    int C, int N, long long in_stride, long long out_stride) {
  int e = blockIdx.z;
  const float* src = in + (long long)e * in_stride;
  short* dst = outp + (long long)e * out_stride;
  int n0 = blockIdx.x * 64, c0 = blockIdx.y * 64;
  __shared__ unsigned ldsb[64][34];  // [n][c-pair], +2 pad
  int t = threadIdx.x;
  int n4 = t & 15;   // 4-float group along n
  int kp = t >> 4;   // c-pair index 0..15
  #pragma unroll
  for (int p = 0; p < 2; ++p) {
    int c = c0 + p * 32 + 2 * kp;
    const float* s0 = src + (long long)c * N + n0 + 4 * n4;
    float4 a = *(const float4*)s0;
    float4 b = *(const float4*)(s0 + N);
    int cc = p * 16 + kp;
    ldsb[4 * n4 + 0][cc] = packbf2(a.x, b.x);
    ldsb[4 * n4 + 1][cc] = packbf2(a.y, b.y);
    ldsb[4 * n4 + 2][cc] = packbf2(a.z, b.z);
    ldsb[4 * n4 + 3][cc] = packbf2(a.w, b.w);
  }
  __syncthreads();
  int ch = t & 7;          // 16B chunk (8 c-elements)
  int nr = t >> 3;         // 0..31
  #pragma unroll
  for (int p = 0; p < 2; ++p) {
    int n = p * 32 + nr;
    uint4 v;
    v.x = ldsb[n][4 * ch + 0]; v.y = ldsb[n][4 * ch + 1];
    v.z = ldsb[n][4 * ch + 2]; v.w = ldsb[n][4 * ch + 3];
    *(uint4*)(dst + (size_t)(n0 + n) * C + c0 + 8 * ch) = v;
  }
}

// ---------------- gating: fp64 logits + softmax + group top-3 + top-6 ----------------
__global__ __launch_bounds__(64) void gating_kernel(const float* __restrict__ x,
                                                    const float* __restrict__ gw,
                                                    int* __restrict__ tidx,
                                                    float* __restrict__ tw) {
  int t = blockIdx.x;
  int lane = threadIdx.x;
  int e = lane & 31, half = lane >> 5;
  const float* xr = x + (size_t)t * H;
  const float* wr = gw + (size_t)e * H;
  const float4* xr4 = (const float4*)(xr + half * 512);
  const float4* wr4 = (const float4*)(wr + half * 512);
  double acc = 0.0;
  #pragma unroll 4
  for (int j = 0; j < 128; ++j) {
    float4 a = xr4[j], b = wr4[j];
    acc += (double)a.x * b.x + (double)a.y * b.y + (double)a.z * b.z + (double)a.w * b.w;
  }
  acc += __shfl_down(acc, 32);
  __shared__ double sc[32];
  if (lane < 32) sc[lane] = acc;
  __syncthreads();
  if (lane == 0) {
    double p[32];
    double m = -1e300;
    for (int i = 0; i < 32; ++i) if (sc[i] > m) m = sc[i];
    double sum = 0.0;
    for (int i = 0; i < 32; ++i) { p[i] = exp(sc[i] - m); sum += p[i]; }
    for (int i = 0; i < 32; ++i) p[i] /= sum;
    double gs[8];
    for (int g = 0; g < 8; ++g) {
      double mm = p[4 * g];
      for (int j = 1; j < 4; ++j) if (p[4 * g + j] > mm) mm = p[4 * g + j];
      gs[g] = mm;
    }
    bool gsel[8] = {false,false,false,false,false,false,false,false};
    for (int it = 0; it < TOPK_GROUP; ++it) {
      int best = -1; double bv = -1e300;
      for (int g = 0; g < 8; ++g) if (!gsel[g] && gs[g] > bv) { bv = gs[g]; best = g; }
      gsel[best] = true;
    }
    double mp[32];
    for (int i = 0; i < 32; ++i) mp[i] = gsel[i >> 2] ? p[i] : 0.0;
    for (int it = 0; it < K_TOP; ++it) {
      int best = -1; double bv = -1e300;
      for (int i = 0; i < 32; ++i) if (mp[i] > bv) { bv = mp[i]; best = i; }
      tidx[t * K_TOP + it] = best;
      tw[t * K_TOP + it] = (float)bv;  // SCALE = 1.0
      mp[best] = -2.0;
    }
  }
}

// ---------------- dispatch: stable flat-order compaction per expert ----------------
__global__ __launch_bounds__(64) void dispatch_kernel(const int* __restrict__ tidx,
                                                      const float* __restrict__ tw,
                                                      int* __restrict__ token_list,
                                                      float* __restrict__ slot_w,
                                                      int* __restrict__ cnt) {
  int e = blockIdx.x;
  int lane = threadIdx.x;
  int base = 0;
  for (int c = 0; c < T_TOK * K_TOP; c += 64) {
    int idx = c + lane;
    int te = tidx[idx];
    bool m = (te == e);
    unsigned long long bal = __ballot(m);
    if (m) {
      int pos = base + __popcll(bal & ((1ull << lane) - 1ull));
      if (pos < CAP) {
        token_list[e * CAP + pos] = idx / K_TOP;
        slot_w[e * CAP + pos] = tw[idx];
      }
    }
    base += __popcll(bal);
  }
  if (lane == 0) cnt[e] = base < CAP ? base : CAP;
}

// ---------------- fused gate+up GEMM -> S = silu(g)*u (bf16) ----------------
// 128x64 tile, 4 waves (2x2), 16x16x32 MFMA, global_load_lds staging, Kdim = H.
__global__ __launch_bounds__(256) void gateup_kernel(
    const short* __restrict__ Xb, const short* __restrict__ WgT, const short* __restrict__ WuT,
    short* __restrict__ Sout, const int* __restrict__ tlist, const int* __restrict__ cnt_dev,
    int Nld, long long wstride, long long sstride) {
  int e = blockIdx.z;
  int cnt = cnt_dev ? cnt_dev[e] : T_TOK;
  int row0 = blockIdx.y * 128;
  if (row0 >= cnt) return;
  int col0 = blockIdx.x * 64;
  const short* wg = WgT + (long long)e * wstride;
  const short* wu = WuT + (long long)e * wstride;
  short* sbase = Sout + (long long)e * sstride;

  __shared__ __align__(16) short As[128 * 32];
  __shared__ __align__(16) short Bgs[64 * 32];
  __shared__ __align__(16) short Bus[64 * 32];

  int tid = threadIdx.x;
  int lane = tid & 63, wave = tid >> 6;
  int rr = tid >> 2, ch = tid & 3;

  int ra0 = row0 + rr, ra1 = ra0 + 64;
  if (tlist) {
    const int* tl = tlist + e * CAP;
    ra0 = tl[min(ra0, cnt - 1)];
    ra1 = tl[min(ra1, cnt - 1)];
  }
  const short* pa0 = Xb + (size_t)ra0 * H + ch * 8;
  const short* pa1 = Xb + (size_t)ra1 * H + ch * 8;
  const short* pbg = wg + (size_t)(col0 + rr) * H + ch * 8;
  const short* pbu = wu + (size_t)(col0 + rr) * H + ch * 8;

  short* ldsA0 = &As[(wave * 16) * 32];
  short* ldsA1 = &As[(64 + wave * 16) * 32];
  short* ldsBg = &Bgs[(wave * 16) * 32];
  short* ldsBu = &Bus[(wave * 16) * 32];

  int wm = wave & 1, wn = wave >> 1;
  int c = lane & 15, q = lane >> 4;
  const short* fA = &As[(wm * 64 + c) * 32 + q * 8];
  const short* fBg = &Bgs[(wn * 32 + c) * 32 + q * 8];
  const short* fBu = &Bus[(wn * 32 + c) * 32 + q * 8];

  f32x4 accg[4][2], accu[4][2];
  #pragma unroll
  for (int i = 0; i < 4; ++i)
    #pragma unroll
    for (int j = 0; j < 2; ++j) {
      accg[i][j] = (f32x4){0.f, 0.f, 0.f, 0.f};
      accu[i][j] = (f32x4){0.f, 0.f, 0.f, 0.f};
    }

  for (int k0 = 0; k0 < H; k0 += 32) {
    __syncthreads();
    gload_lds16(pa0 + k0, ldsA0);
    gload_lds16(pa1 + k0, ldsA1);
    gload_lds16(pbg + k0, ldsBg);
    gload_lds16(pbu + k0, ldsBu);
    __syncthreads();
    short8v a[4], bg[2], bu[2];
    #pragma unroll
    for (int mi = 0; mi < 4; ++mi) a[mi] = *(const short8v*)(fA + mi * 16 * 32);
    #pragma unroll
    for (int ni = 0; ni < 2; ++ni) {
      bg[ni] = *(const short8v*)(fBg + ni * 16 * 32);
      bu[ni] = *(const short8v*)(fBu + ni * 16 * 32);
    }
    #pragma unroll
    for (int mi = 0; mi < 4; ++mi)
      #pragma unroll
      for (int ni = 0; ni < 2; ++ni) {
        accg[mi][ni] = __builtin_amdgcn_mfma_f32_16x16x32_bf16(a[mi], bg[ni], accg[mi][ni], 0, 0, 0);
        accu[mi][ni] = __builtin_amdgcn_mfma_f32_16x16x32_bf16(a[mi], bu[ni], accu[mi][ni], 0, 0, 0);
      }
  }
  // epilogue: S = silu(g)*u  (C/D: row = q*4+reg, col = lane&15)
  #pragma unroll
  for (int mi = 0; mi < 4; ++mi) {
    int rbase = row0 + wm * 64 + mi * 16 + q * 4;
    #pragma unroll
    for (int ni = 0; ni < 2; ++ni) {
      int col = col0 + wn * 32 + ni * 16 + c;
      #pragma unroll
      for (int r = 0; r < 4; ++r) {
        float g = accg[mi][ni][r], u = accu[mi][ni][r];
        float s = (g / (1.f + __expf(-g))) * u;
        sbase[(size_t)(rbase + r) * Nld + col] = (short)f2bfbits(s);
      }
    }
  }
}

// ---------------- down GEMM: Y = S @ WdT^T; scatter-add (routed) or store (shared) ----------------
// 128x128 tile, 4 waves (2x2), m97 structure.
__global__ __launch_bounds__(256) void down_kernel(
    const short* __restrict__ Sin, const short* __restrict__ WdT, float* __restrict__ out,
    const int* __restrict__ tlist, const float* __restrict__ slot_w, const int* __restrict__ cnt_dev,
    int Kdim, long long wstride, long long sstride) {
  int e = blockIdx.z;
  int cnt = cnt_dev ? cnt_dev[e] : T_TOK;
  int row0 = blockIdx.y * 128;
  if (row0 >= cnt) return;
  int col0 = blockIdx.x * 128;
  const short* sb = Sin + (long long)e * sstride;
  const short* wd = WdT + (long long)e * wstride;

  __shared__ __align__(16) short As[128 * 32];
  __shared__ __align__(16) short Bs[128 * 32];

  int tid = threadIdx.x;
  int lane = tid & 63, wave = tid >> 6;
  int rr = tid >> 2, ch = tid & 3;

  const short* pa0 = sb + (size_t)(row0 + rr) * Kdim + ch * 8;
  const short* pa1 = pa0 + (size_t)64 * Kdim;
  const short* pb0 = wd + (size_t)(col0 + rr) * Kdim + ch * 8;
  const short* pb1 = pb0 + (size_t)64 * Kdim;

  short* ldsA0 = &As[(wave * 16) * 32];
  short* ldsA1 = &As[(64 + wave * 16) * 32];
  short* ldsB0 = &Bs[(wave * 16) * 32];
  short* ldsB1 = &Bs[(64 + wave * 16) * 32];

  int wm = wave & 1, wn = wave >> 1;
  int c = lane & 15, q = lane >> 4;
  const short* fA = &As[(wm * 64 + c) * 32 + q * 8];
  const short* fB = &Bs[(wn * 64 + c) * 32 + q * 8];

  f32x4 acc[4][4];
  #pragma unroll
  for (int i = 0; i < 4; ++i)
    #pragma unroll
    for (int j = 0; j < 4; ++j) acc[i][j] = (f32x4){0.f, 0.f, 0.f, 0.f};

  for (int k0 = 0; k0 < Kdim; k0 += 32) {
    __syncthreads();
    gload_lds16(pa0 + k0, ldsA0);
    gload_lds16(pa1 + k0, ldsA1);
    gload_lds16(pb0 + k0, ldsB0);
    gload_lds16(pb1 + k0, ldsB1);
    __syncthreads();
    short8v a[4], b[4];
    #pragma unroll
    for (int mi = 0; mi < 4; ++mi) a[mi] = *(const short8v*)(fA + mi * 16 * 32);
    #pragma unroll
    for (int ni = 0; ni < 4; ++ni) b[ni] = *(const short8v*)(fB + ni * 16 * 32);
    #pragma unroll
    for (int mi = 0; mi < 4; ++mi)
      #pragma unroll
      for (int ni = 0; ni < 4; ++ni)
        acc[mi][ni] = __builtin_amdgcn_mfma_f32_16x16x32_bf16(a[mi], b[ni], acc[mi][ni], 0, 0, 0);
  }

  if (tlist) {
    const int* tl = tlist + e * CAP;
    const float* swt = slot_w + e * CAP;
    #pragma unroll
    for (int mi = 0; mi < 4; ++mi) {
      int rb = row0 + wm * 64 + mi * 16 + q * 4;
      #pragma unroll
      for (int r = 0; r < 4; ++r) {
        int s = rb + r;
        if (s < cnt) {
          int tkn = tl[s];
          float w = swt[s];
          #pragma unroll
          for (int ni = 0; ni < 4; ++ni) {
            int col = col0 + wn * 64 + ni * 16 + c;
            atomicAdd(&out[(size_t)tkn * H + col], w * acc[mi][ni][r]);
          }
        }
      }
    }
  } else {
    #pragma unroll
    for (int mi = 0; mi < 4; ++mi) {
      int rb = row0 + wm * 64 + mi * 16 + q * 4;
      #pragma unroll
      for (int ni = 0; ni < 4; ++ni) {
        int col = col0 + wn * 64 + ni * 16 + c;
        #pragma unroll
        for (int r = 0; r < 4; ++r)
          out[(size_t)(rb + r) * H + col] = acc[mi][ni][r];
      }
    }
  }
}

extern "C" void kernel_launch(void* const* d_in, const int* in_sizes, int n_in,
                              void* d_out, int out_size, void* d_ws, size_t ws_size,
                              hipStream_t stream) {
  const float* x       = (const float*)d_in[0];
  const float* gate_w  = (const float*)d_in[1];
  const float* w_gate  = (const float*)d_in[2];
  const float* w_up    = (const float*)d_in[3];
  const float* w_down  = (const float*)d_in[4];
  const float* sw_gate = (const float*)d_in[5];
  const float* sw_up   = (const float*)d_in[6];
  const float* sw_down = (const float*)d_in[7];
  float* out = (float*)d_out;
  char* ws = (char*)d_ws;

  size_t o = 0;
  short* xb   = (short*)(ws + o); o += (size_t)T_TOK * H * 2;
  short* Sr   = (short*)(ws + o); o += (size_t)E * CAP * I_DIM * 2;
  short* Ss   = (short*)(ws + o); o += (size_t)T_TOK * IS_DIM * 2;
  short* wgT  = (short*)(ws + o); o += (size_t)E * I_DIM * H * 2;
  short* wuT  = (short*)(ws + o); o += (size_t)E * I_DIM * H * 2;
  short* wdT  = (short*)(ws + o); o += (size_t)E * H * I_DIM * 2;
  short* swgT = (short*)(ws + o); o += (size_t)IS_DIM * H * 2;
  short* swuT = (short*)(ws + o); o += (size_t)IS_DIM * H * 2;
  short* swdT = (short*)(ws + o); o += (size_t)H * IS_DIM * 2;
  int*   tidx = (int*)(ws + o);   o += (size_t)T_TOK * K_TOP * 4;
  float* twt  = (float*)(ws + o); o += (size_t)T_TOK * K_TOP * 4;
  int*   tl   = (int*)(ws + o);   o += (size_t)E * CAP * 4;
  float* swt  = (float*)(ws + o); o += (size_t)E * CAP * 4;
  int*   cnt  = (int*)(ws + o);   o += 256;

  cast_x_kernel<<<(T_TOK * H) / 1024, 256, 0, stream>>>(x, xb);
  gating_kernel<<<T_TOK, 64, 0, stream>>>(x, gate_w, tidx, twt);
  dispatch_kernel<<<E, 64, 0, stream>>>(tidx, twt, tl, swt, cnt);

  // weight transposes: in [C][N] fp32 -> out [N][C] bf16
  transpose_cast_kernel<<<dim3(I_DIM / 64, H / 64, E), 256, 0, stream>>>(
      w_gate, wgT, H, I_DIM, (long long)H * I_DIM, (long long)I_DIM * H);
  transpose_cast_kernel<<<dim3(I_DIM / 64, H / 64, E), 256, 0, stream>>>(
      w_up, wuT, H, I_DIM, (long long)H * I_DIM, (long long)I_DIM * H);
  transpose_cast_kernel<<<dim3(H / 64, I_DIM / 64, E), 256, 0, stream>>>(
      w_down, wdT, I_DIM, H, (long long)I_DIM * H, (long long)H * I_DIM);
  transpose_cast_kernel<<<dim3(IS_DIM / 64, H / 64, 1), 256, 0, stream>>>(
      sw_gate, swgT, H, IS_DIM, 0, 0);
  transpose_cast_kernel<<<dim3(IS_DIM / 64, H / 64, 1), 256, 0, stream>>>(
      sw_up, swuT, H, IS_DIM, 0, 0);
  transpose_cast_kernel<<<dim3(H / 64, IS_DIM / 64, 1), 256, 0, stream>>>(
      sw_down, swdT, IS_DIM, H, 0, 0);

  // routed gate+up -> Sr
  gateup_kernel<<<dim3(I_DIM / 64, CAP / 128, E), 256, 0, stream>>>(
      xb, wgT, wuT, Sr, tl, cnt, I_DIM, (long long)I_DIM * H, (long long)CAP * I_DIM);
  // shared gate+up -> Ss
  gateup_kernel<<<dim3(IS_DIM / 64, T_TOK / 128, 1), 256, 0, stream>>>(
      xb, swgT, swuT, Ss, nullptr, nullptr, IS_DIM, 0, 0);
  // shared down: plain store, fully initializes out
  down_kernel<<<dim3(H / 128, T_TOK / 128, 1), 256, 0, stream>>>(
      Ss, swdT, out, nullptr, nullptr, nullptr, IS_DIM, 0, 0);
  // routed down: atomic scatter-add
  down_kernel<<<dim3(H / 128, CAP / 128, E), 256, 0, stream>>>(
      Sr, wdT, out, tl, swt, cnt, I_DIM, (long long)H * I_DIM, (long long)CAP * I_DIM);
}

// Round 3
// 564.237 us; speedup vs baseline: 1.3624x; 1.1772x over previous
//
#include <hip/hip_runtime.h>
#include <hip/hip_bf16.h>

#define H 1024
#define I_DIM 704
#define E 32
#define TOPK_GROUP 3
#define K_TOP 6
#define T_TOK 2048
#define CAP 768
#define IS_DIM 1408   // N_SHARED * I
#define NCHUNK 192    // (T_TOK*K_TOP)/64

typedef __attribute__((ext_vector_type(8))) short short8v;
typedef __attribute__((ext_vector_type(4))) float f32x4;

__device__ __forceinline__ unsigned short f2bfbits(float f) {
  unsigned u = __float_as_uint(f);
  unsigned r = (u + 0x7fffu + ((u >> 16) & 1u)) >> 16;  // RTNE
  return (unsigned short)r;
}
__device__ __forceinline__ unsigned packbf2(float lo, float hi) {
  return (unsigned)f2bfbits(lo) | ((unsigned)f2bfbits(hi) << 16);
}
__device__ __forceinline__ void gload_lds16(const short* g, short* l) {
  __builtin_amdgcn_global_load_lds(
      (const __attribute__((address_space(1))) unsigned int*)g,
      (__attribute__((address_space(3))) unsigned int*)l, 16, 0, 0);
}

// ---------------- cast x (fp32) -> bf16 bits ----------------
__global__ void cast_x_kernel(const float* __restrict__ x, short* __restrict__ xb) {
  size_t i = ((size_t)blockIdx.x * 256 + threadIdx.x) * 4;
  float4 v = *(const float4*)(x + i);
  short4 s;
  s.x = (short)f2bfbits(v.x); s.y = (short)f2bfbits(v.y);
  s.z = (short)f2bfbits(v.z); s.w = (short)f2bfbits(v.w);
  *(short4*)(xb + i) = s;
}

// ---------------- transpose + cast: in [C][N] fp32 -> out [N][C] bf16 ----------------
__global__ __launch_bounds__(256) void transpose_cast_kernel(
    const float* __restrict__ in, short* __restrict__ outp,
    int C, int N, long long in_stride, long long out_stride) {
  int e = blockIdx.z;
  const float* src = in + (long long)e * in_stride;
  short* dst = outp + (long long)e * out_stride;
  int n0 = blockIdx.x * 64, c0 = blockIdx.y * 64;
  __shared__ unsigned ldsb[64][34];
  int t = threadIdx.x;
  int n4 = t & 15;
  int kp = t >> 4;
  #pragma unroll
  for (int p = 0; p < 2; ++p) {
    int c = c0 + p * 32 + 2 * kp;
    const float* s0 = src + (long long)c * N + n0 + 4 * n4;
    float4 a = *(const float4*)s0;
    float4 b = *(const float4*)(s0 + N);
    int cc = p * 16 + kp;
    ldsb[4 * n4 + 0][cc] = packbf2(a.x, b.x);
    ldsb[4 * n4 + 1][cc] = packbf2(a.y, b.y);
    ldsb[4 * n4 + 2][cc] = packbf2(a.z, b.z);
    ldsb[4 * n4 + 3][cc] = packbf2(a.w, b.w);
  }
  __syncthreads();
  int ch = t & 7;
  int nr = t >> 3;
  #pragma unroll
  for (int p = 0; p < 2; ++p) {
    int n = p * 32 + nr;
    uint4 v;
    v.x = ldsb[n][4 * ch + 0]; v.y = ldsb[n][4 * ch + 1];
    v.z = ldsb[n][4 * ch + 2]; v.w = ldsb[n][4 * ch + 3];
    *(uint4*)(dst + (size_t)(n0 + n) * C + c0 + 8 * ch) = v;
  }
}

// ---------------- gating: fp64 logits, lane-parallel softmax + group top-3 + top-6 ----------------
__global__ __launch_bounds__(64) void gating_kernel(const float* __restrict__ x,
                                                    const float* __restrict__ gw,
                                                    int* __restrict__ tidx,
                                                    float* __restrict__ tw) {
  int t = blockIdx.x;
  int lane = threadIdx.x;
  int e = lane & 31, half = lane >> 5;
  const float4* xr4 = (const float4*)(x + (size_t)t * H + half * 512);
  const float4* wr4 = (const float4*)(gw + (size_t)e * H + half * 512);
  double acc = 0.0;
  #pragma unroll 4
  for (int j = 0; j < 128; ++j) {
    float4 a = xr4[j], b = wr4[j];
    acc += (double)a.x * b.x + (double)a.y * b.y + (double)a.z * b.z + (double)a.w * b.w;
  }
  acc += __shfl_down(acc, 32);   // lanes 0..31 now hold the 32 logits
  double lg = acc;
  // max over 32 lanes (xor<32 keeps halves independent; upper half computes garbage, writes nothing)
  double m = lg;
  #pragma unroll
  for (int off = 16; off >= 1; off >>= 1) {
    double o = __shfl_xor(m, off);
    if (o > m) m = o;
  }
  double p = exp(lg - m);
  double sum = p;
  #pragma unroll
  for (int off = 16; off >= 1; off >>= 1) sum += __shfl_xor(sum, off);
  p /= sum;
  // group max over each quad of 4 experts
  double gmax = p;
  { double o = __shfl_xor(gmax, 1); if (o > gmax) gmax = o;
    o = __shfl_xor(gmax, 2); if (o > gmax) gmax = o; }
  // top-3 groups: lexicographic (value desc, group index asc) shuffle reduce, 3 rounds
  bool gsel = false;
  double gv = gmax;
  #pragma unroll
  for (int it = 0; it < TOPK_GROUP; ++it) {
    double v = gv; int gi = e >> 2;
    #pragma unroll
    for (int off = 16; off >= 1; off >>= 1) {
      double ov = __shfl_xor(v, off);
      int oi = __shfl_xor(gi, off);
      if (ov > v || (ov == v && oi < gi)) { v = ov; gi = oi; }
    }
    if ((e >> 2) == gi) { gsel = true; gv = -1e300; }
  }
  double mp = gsel ? p : 0.0;
  // top-6 experts
  #pragma unroll
  for (int it = 0; it < K_TOP; ++it) {
    double v = mp; int ei = e;
    #pragma unroll
    for (int off = 16; off >= 1; off >>= 1) {
      double ov = __shfl_xor(v, off);
      int oi = __shfl_xor(ei, off);
      if (ov > v || (ov == v && oi < ei)) { v = ov; ei = oi; }
    }
    if (lane == 0) { tidx[t * K_TOP + it] = ei; tw[t * K_TOP + it] = (float)v; }
    if (e == ei) mp = -2.0;
  }
}

// ---------------- dispatch phase 1: per-chunk histograms ----------------
__global__ __launch_bounds__(64) void hist_kernel(const int* __restrict__ tidx,
                                                  int* __restrict__ chunk_hist) {
  __shared__ int h[E];
  int c = blockIdx.x, lane = threadIdx.x;
  if (lane < E) h[lane] = 0;
  __syncthreads();
  int te = tidx[c * 64 + lane];
  atomicAdd(&h[te], 1);
  __syncthreads();
  if (lane < E) chunk_hist[c * E + lane] = h[lane];
}

// ---------------- dispatch phase 2: per-expert exclusive prefix over chunks ----------------
__global__ __launch_bounds__(1024) void scan_kernel(const int* __restrict__ chunk_hist,
                                                    int* __restrict__ chunk_base,
                                                    int* __restrict__ cnt) {
  __shared__ int h[NCHUNK * E];  // 24 KB
  int t = threadIdx.x;
  for (int i = t; i < NCHUNK * E; i += 1024) h[i] = chunk_hist[i];
  __syncthreads();
  if (t < E) {
    int run = 0;
    for (int c = 0; c < NCHUNK; ++c) {
      int v = h[c * E + t];
      h[c * E + t] = run;
      run += v;
    }
    cnt[t] = run < CAP ? run : CAP;
  }
  __syncthreads();
  for (int i = t; i < NCHUNK * E; i += 1024) chunk_base[i] = h[i];
}

// ---------------- dispatch phase 3: placement ----------------
__global__ __launch_bounds__(64) void place_kernel(const int* __restrict__ tidx,
                                                   const float* __restrict__ tw,
                                                   const int* __restrict__ chunk_base,
                                                   int* __restrict__ token_list,
                                                   float* __restrict__ slot_w) {
  int c = blockIdx.x, lane = threadIdx.x;
  int idx = c * 64 + lane;
  int te = tidx[idx];
  unsigned long long mymask = 0;
  #pragma unroll
  for (int e = 0; e < E; ++e) {
    unsigned long long bal = __ballot(te == e);
    if (te == e) mymask = bal;
  }
  int rank = __popcll(mymask & ((1ull << lane) - 1ull));
  int pos = chunk_base[c * E + te] + rank;
  if (pos < CAP) {
    token_list[te * CAP + pos] = idx / K_TOP;
    slot_w[te * CAP + pos] = tw[idx];
  }
}

// ---------------- fused gate+up GEMM -> S = silu(g)*u (bf16) ----------------
__global__ __launch_bounds__(256) void gateup_kernel(
    const short* __restrict__ Xb, const short* __restrict__ WgT, const short* __restrict__ WuT,
    short* __restrict__ Sout, const int* __restrict__ tlist, const int* __restrict__ cnt_dev,
    int Nld, long long wstride, long long sstride) {
  int e = blockIdx.z;
  int cnt = cnt_dev ? cnt_dev[e] : T_TOK;
  int row0 = blockIdx.y * 128;
  if (row0 >= cnt) return;
  int col0 = blockIdx.x * 64;
  const short* wg = WgT + (long long)e * wstride;
  const short* wu = WuT + (long long)e * wstride;
  short* sbase = Sout + (long long)e * sstride;

  __shared__ __align__(16) short As[128 * 32];
  __shared__ __align__(16) short Bgs[64 * 32];
  __shared__ __align__(16) short Bus[64 * 32];

  int tid = threadIdx.x;
  int lane = tid & 63, wave = tid >> 6;
  int rr = tid >> 2, ch = tid & 3;

  int ra0 = row0 + rr, ra1 = ra0 + 64;
  if (tlist) {
    const int* tl = tlist + e * CAP;
    ra0 = tl[min(ra0, cnt - 1)];
    ra1 = tl[min(ra1, cnt - 1)];
  }
  const short* pa0 = Xb + (size_t)ra0 * H + ch * 8;
  const short* pa1 = Xb + (size_t)ra1 * H + ch * 8;
  const short* pbg = wg + (size_t)(col0 + rr) * H + ch * 8;
  const short* pbu = wu + (size_t)(col0 + rr) * H + ch * 8;

  short* ldsA0 = &As[(wave * 16) * 32];
  short* ldsA1 = &As[(64 + wave * 16) * 32];
  short* ldsBg = &Bgs[(wave * 16) * 32];
  short* ldsBu = &Bus[(wave * 16) * 32];

  int wm = wave & 1, wn = wave >> 1;
  int c = lane & 15, q = lane >> 4;
  const short* fA = &As[(wm * 64 + c) * 32 + q * 8];
  const short* fBg = &Bgs[(wn * 32 + c) * 32 + q * 8];
  const short* fBu = &Bus[(wn * 32 + c) * 32 + q * 8];

  f32x4 accg[4][2], accu[4][2];
  #pragma unroll
  for (int i = 0; i < 4; ++i)
    #pragma unroll
    for (int j = 0; j < 2; ++j) {
      accg[i][j] = (f32x4){0.f, 0.f, 0.f, 0.f};
      accu[i][j] = (f32x4){0.f, 0.f, 0.f, 0.f};
    }

  for (int k0 = 0; k0 < H; k0 += 32) {
    __syncthreads();
    gload_lds16(pa0 + k0, ldsA0);
    gload_lds16(pa1 + k0, ldsA1);
    gload_lds16(pbg + k0, ldsBg);
    gload_lds16(pbu + k0, ldsBu);
    __syncthreads();
    short8v a[4], bg[2], bu[2];
    #pragma unroll
    for (int mi = 0; mi < 4; ++mi) a[mi] = *(const short8v*)(fA + mi * 16 * 32);
    #pragma unroll
    for (int ni = 0; ni < 2; ++ni) {
      bg[ni] = *(const short8v*)(fBg + ni * 16 * 32);
      bu[ni] = *(const short8v*)(fBu + ni * 16 * 32);
    }
    #pragma unroll
    for (int mi = 0; mi < 4; ++mi)
      #pragma unroll
      for (int ni = 0; ni < 2; ++ni) {
        accg[mi][ni] = __builtin_amdgcn_mfma_f32_16x16x32_bf16(a[mi], bg[ni], accg[mi][ni], 0, 0, 0);
        accu[mi][ni] = __builtin_amdgcn_mfma_f32_16x16x32_bf16(a[mi], bu[ni], accu[mi][ni], 0, 0, 0);
      }
  }
  #pragma unroll
  for (int mi = 0; mi < 4; ++mi) {
    int rbase = row0 + wm * 64 + mi * 16 + q * 4;
    #pragma unroll
    for (int ni = 0; ni < 2; ++ni) {
      int col = col0 + wn * 32 + ni * 16 + c;
      #pragma unroll
      for (int r = 0; r < 4; ++r) {
        float g = accg[mi][ni][r], u = accu[mi][ni][r];
        float s = (g / (1.f + __expf(-g))) * u;
        sbase[(size_t)(rbase + r) * Nld + col] = (short)f2bfbits(s);
      }
    }
  }
}

// ---------------- down GEMM: Y = S @ WdT^T; scatter-add (routed) or store (shared) ----------------
__global__ __launch_bounds__(256) void down_kernel(
    const short* __restrict__ Sin, const short* __restrict__ WdT, float* __restrict__ out,
    const int* __restrict__ tlist, const float* __restrict__ slot_w, const int* __restrict__ cnt_dev,
    int Kdim, long long wstride, long long sstride) {
  int e = blockIdx.z;
  int cnt = cnt_dev ? cnt_dev[e] : T_TOK;
  int row0 = blockIdx.y * 128;
  if (row0 >= cnt) return;
  int col0 = blockIdx.x * 128;
  const short* sb = Sin + (long long)e * sstride;
  const short* wd = WdT + (long long)e * wstride;

  __shared__ __align__(16) short As[128 * 32];
  __shared__ __align__(16) short Bs[128 * 32];

  int tid = threadIdx.x;
  int lane = tid & 63, wave = tid >> 6;
  int rr = tid >> 2, ch = tid & 3;

  const short* pa0 = sb + (size_t)(row0 + rr) * Kdim + ch * 8;
  const short* pa1 = pa0 + (size_t)64 * Kdim;
  const short* pb0 = wd + (size_t)(col0 + rr) * Kdim + ch * 8;
  const short* pb1 = pb0 + (size_t)64 * Kdim;

  short* ldsA0 = &As[(wave * 16) * 32];
  short* ldsA1 = &As[(64 + wave * 16) * 32];
  short* ldsB0 = &Bs[(wave * 16) * 32];
  short* ldsB1 = &Bs[(64 + wave * 16) * 32];

  int wm = wave & 1, wn = wave >> 1;
  int c = lane & 15, q = lane >> 4;
  const short* fA = &As[(wm * 64 + c) * 32 + q * 8];
  const short* fB = &Bs[(wn * 64 + c) * 32 + q * 8];

  f32x4 acc[4][4];
  #pragma unroll
  for (int i = 0; i < 4; ++i)
    #pragma unroll
    for (int j = 0; j < 4; ++j) acc[i][j] = (f32x4){0.f, 0.f, 0.f, 0.f};

  for (int k0 = 0; k0 < Kdim; k0 += 32) {
    __syncthreads();
    gload_lds16(pa0 + k0, ldsA0);
    gload_lds16(pa1 + k0, ldsA1);
    gload_lds16(pb0 + k0, ldsB0);
    gload_lds16(pb1 + k0, ldsB1);
    __syncthreads();
    short8v a[4], b[4];
    #pragma unroll
    for (int mi = 0; mi < 4; ++mi) a[mi] = *(const short8v*)(fA + mi * 16 * 32);
    #pragma unroll
    for (int ni = 0; ni < 4; ++ni) b[ni] = *(const short8v*)(fB + ni * 16 * 32);
    #pragma unroll
    for (int mi = 0; mi < 4; ++mi)
      #pragma unroll
      for (int ni = 0; ni < 4; ++ni)
        acc[mi][ni] = __builtin_amdgcn_mfma_f32_16x16x32_bf16(a[mi], b[ni], acc[mi][ni], 0, 0, 0);
  }

  if (tlist) {
    const int* tl = tlist + e * CAP;
    const float* swt = slot_w + e * CAP;
    #pragma unroll
    for (int mi = 0; mi < 4; ++mi) {
      int rb = row0 + wm * 64 + mi * 16 + q * 4;
      #pragma unroll
      for (int r = 0; r < 4; ++r) {
        int s = rb + r;
        if (s < cnt) {
          int tkn = tl[s];
          float w = swt[s];
          #pragma unroll
          for (int ni = 0; ni < 4; ++ni) {
            int col = col0 + wn * 64 + ni * 16 + c;
            atomicAdd(&out[(size_t)tkn * H + col], w * acc[mi][ni][r]);
          }
        }
      }
    }
  } else {
    #pragma unroll
    for (int mi = 0; mi < 4; ++mi) {
      int rb = row0 + wm * 64 + mi * 16 + q * 4;
      #pragma unroll
      for (int ni = 0; ni < 4; ++ni) {
        int col = col0 + wn * 64 + ni * 16 + c;
        #pragma unroll
        for (int r = 0; r < 4; ++r)
          out[(size_t)(rb + r) * H + col] = acc[mi][ni][r];
      }
    }
  }
}

extern "C" void kernel_launch(void* const* d_in, const int* in_sizes, int n_in,
                              void* d_out, int out_size, void* d_ws, size_t ws_size,
                              hipStream_t stream) {
  const float* x       = (const float*)d_in[0];
  const float* gate_w  = (const float*)d_in[1];
  const float* w_gate  = (const float*)d_in[2];
  const float* w_up    = (const float*)d_in[3];
  const float* w_down  = (const float*)d_in[4];
  const float* sw_gate = (const float*)d_in[5];
  const float* sw_up   = (const float*)d_in[6];
  const float* sw_down = (const float*)d_in[7];
  float* out = (float*)d_out;
  char* ws = (char*)d_ws;

  size_t o = 0;
  short* xb   = (short*)(ws + o); o += (size_t)T_TOK * H * 2;
  short* Sr   = (short*)(ws + o); o += (size_t)E * CAP * I_DIM * 2;
  short* Ss   = (short*)(ws + o); o += (size_t)T_TOK * IS_DIM * 2;
  short* wgT  = (short*)(ws + o); o += (size_t)E * I_DIM * H * 2;
  short* wuT  = (short*)(ws + o); o += (size_t)E * I_DIM * H * 2;
  short* wdT  = (short*)(ws + o); o += (size_t)E * H * I_DIM * 2;
  short* swgT = (short*)(ws + o); o += (size_t)IS_DIM * H * 2;
  short* swuT = (short*)(ws + o); o += (size_t)IS_DIM * H * 2;
  short* swdT = (short*)(ws + o); o += (size_t)H * IS_DIM * 2;
  int*   tidx = (int*)(ws + o);   o += (size_t)T_TOK * K_TOP * 4;
  float* twt  = (float*)(ws + o); o += (size_t)T_TOK * K_TOP * 4;
  int*   tl   = (int*)(ws + o);   o += (size_t)E * CAP * 4;
  float* swt  = (float*)(ws + o); o += (size_t)E * CAP * 4;
  int*   cnt  = (int*)(ws + o);   o += 256;
  int*   chist = (int*)(ws + o);  o += (size_t)NCHUNK * E * 4;
  int*   cbase = (int*)(ws + o);  o += (size_t)NCHUNK * E * 4;

  cast_x_kernel<<<(T_TOK * H) / 1024, 256, 0, stream>>>(x, xb);
  gating_kernel<<<T_TOK, 64, 0, stream>>>(x, gate_w, tidx, twt);
  hist_kernel<<<NCHUNK, 64, 0, stream>>>(tidx, chist);
  scan_kernel<<<1, 1024, 0, stream>>>(chist, cbase, cnt);
  place_kernel<<<NCHUNK, 64, 0, stream>>>(tidx, twt, cbase, tl, swt);

  transpose_cast_kernel<<<dim3(I_DIM / 64, H / 64, E), 256, 0, stream>>>(
      w_gate, wgT, H, I_DIM, (long long)H * I_DIM, (long long)I_DIM * H);
  transpose_cast_kernel<<<dim3(I_DIM / 64, H / 64, E), 256, 0, stream>>>(
      w_up, wuT, H, I_DIM, (long long)H * I_DIM, (long long)I_DIM * H);
  transpose_cast_kernel<<<dim3(H / 64, I_DIM / 64, E), 256, 0, stream>>>(
      w_down, wdT, I_DIM, H, (long long)I_DIM * H, (long long)H * I_DIM);
  transpose_cast_kernel<<<dim3(IS_DIM / 64, H / 64, 1), 256, 0, stream>>>(
      sw_gate, swgT, H, IS_DIM, 0, 0);
  transpose_cast_kernel<<<dim3(IS_DIM / 64, H / 64, 1), 256, 0, stream>>>(
      sw_up, swuT, H, IS_DIM, 0, 0);
  transpose_cast_kernel<<<dim3(H / 64, IS_DIM / 64, 1), 256, 0, stream>>>(
      sw_down, swdT, IS_DIM, H, 0, 0);

  gateup_kernel<<<dim3(I_DIM / 64, CAP / 128, E), 256, 0, stream>>>(
      xb, wgT, wuT, Sr, tl, cnt, I_DIM, (long long)I_DIM * H, (long long)CAP * I_DIM);
  gateup_kernel<<<dim3(IS_DIM / 64, T_TOK / 128, 1), 256, 0, stream>>>(
      xb, swgT, swuT, Ss, nullptr, nullptr, IS_DIM, 0, 0);
  down_kernel<<<dim3(H / 128, T_TOK / 128, 1), 256, 0, stream>>>(
      Ss, swdT, out, nullptr, nullptr, nullptr, IS_DIM, 0, 0);
  down_kernel<<<dim3(H / 128, CAP / 128, E), 256, 0, stream>>>(
      Sr, wdT, out, tl, swt, cnt, I_DIM, (long long)H * I_DIM, (long long)CAP * I_DIM);
}

// Round 4
// 552.655 us; speedup vs baseline: 1.3910x; 1.0210x over previous
//
#include <hip/hip_runtime.h>
#include <hip/hip_bf16.h>

#define H 1024
#define I_DIM 704
#define E 32
#define TOPK_GROUP 3
#define K_TOP 6
#define T_TOK 2048
#define CAP 768
#define IS_DIM 1408   // N_SHARED * I
#define NCHUNK 192    // (T_TOK*K_TOP)/64

typedef __attribute__((ext_vector_type(8))) short short8v;
typedef __attribute__((ext_vector_type(4))) float f32x4;

__device__ __forceinline__ unsigned short f2bfbits(float f) {
  unsigned u = __float_as_uint(f);
  unsigned r = (u + 0x7fffu + ((u >> 16) & 1u)) >> 16;  // RTNE
  return (unsigned short)r;
}
__device__ __forceinline__ unsigned packbf2(float lo, float hi) {
  __hip_bfloat162 h = __float22bfloat162_rn(make_float2(lo, hi));
  unsigned u; __builtin_memcpy(&u, &h, 4); return u;
}
__device__ __forceinline__ float bf2f(unsigned short b) {
  return __uint_as_float(((unsigned)b) << 16);
}
__device__ __forceinline__ void gload_lds16(const short* g, short* l) {
  __builtin_amdgcn_global_load_lds(
      (const __attribute__((address_space(1))) unsigned int*)g,
      (__attribute__((address_space(3))) unsigned int*)l, 16, 0, 0);
}

// ---------------- cast x (fp32) -> bf16 bits ----------------
__global__ void cast_x_kernel(const float* __restrict__ x, short* __restrict__ xb) {
  size_t i = ((size_t)blockIdx.x * 256 + threadIdx.x) * 4;
  float4 v = *(const float4*)(x + i);
  short4 s;
  s.x = (short)f2bfbits(v.x); s.y = (short)f2bfbits(v.y);
  s.z = (short)f2bfbits(v.z); s.w = (short)f2bfbits(v.w);
  *(short4*)(xb + i) = s;
}

// ---------------- gating: fp64 logits, lane-parallel softmax + group top-3 + top-6 ----------------
__global__ __launch_bounds__(64) void gating_kernel(const float* __restrict__ x,
                                                    const float* __restrict__ gw,
                                                    int* __restrict__ tidx,
                                                    float* __restrict__ tw) {
  int t = blockIdx.x;
  int lane = threadIdx.x;
  int e = lane & 31, half = lane >> 5;
  const float4* xr4 = (const float4*)(x + (size_t)t * H + half * 512);
  const float4* wr4 = (const float4*)(gw + (size_t)e * H + half * 512);
  double acc = 0.0;
  #pragma unroll 4
  for (int j = 0; j < 128; ++j) {
    float4 a = xr4[j], b = wr4[j];
    acc += (double)a.x * b.x + (double)a.y * b.y + (double)a.z * b.z + (double)a.w * b.w;
  }
  acc += __shfl_down(acc, 32);   // lanes 0..31 hold the 32 logits
  double lg = acc;
  double m = lg;
  #pragma unroll
  for (int off = 16; off >= 1; off >>= 1) {
    double o = __shfl_xor(m, off);
    if (o > m) m = o;
  }
  double p = exp(lg - m);
  double sum = p;
  #pragma unroll
  for (int off = 16; off >= 1; off >>= 1) sum += __shfl_xor(sum, off);
  p /= sum;
  double gmax = p;
  { double o = __shfl_xor(gmax, 1); if (o > gmax) gmax = o;
    o = __shfl_xor(gmax, 2); if (o > gmax) gmax = o; }
  bool gsel = false;
  double gv = gmax;
  #pragma unroll
  for (int it = 0; it < TOPK_GROUP; ++it) {
    double v = gv; int gi = e >> 2;
    #pragma unroll
    for (int off = 16; off >= 1; off >>= 1) {
      double ov = __shfl_xor(v, off);
      int oi = __shfl_xor(gi, off);
      if (ov > v || (ov == v && oi < gi)) { v = ov; gi = oi; }
    }
    if ((e >> 2) == gi) { gsel = true; gv = -1e300; }
  }
  double mp = gsel ? p : 0.0;
  #pragma unroll
  for (int it = 0; it < K_TOP; ++it) {
    double v = mp; int ei = e;
    #pragma unroll
    for (int off = 16; off >= 1; off >>= 1) {
      double ov = __shfl_xor(v, off);
      int oi = __shfl_xor(ei, off);
      if (ov > v || (ov == v && oi < ei)) { v = ov; ei = oi; }
    }
    if (lane == 0) { tidx[t * K_TOP + it] = ei; tw[t * K_TOP + it] = (float)v; }
    if (e == ei) mp = -2.0;
  }
}

// ---------------- dispatch phase 1: per-chunk histograms ----------------
__global__ __launch_bounds__(64) void hist_kernel(const int* __restrict__ tidx,
                                                  int* __restrict__ chunk_hist) {
  __shared__ int h[E];
  int c = blockIdx.x, lane = threadIdx.x;
  if (lane < E) h[lane] = 0;
  __syncthreads();
  int te = tidx[c * 64 + lane];
  atomicAdd(&h[te], 1);
  __syncthreads();
  if (lane < E) chunk_hist[c * E + lane] = h[lane];
}

// ---------------- dispatch phase 2: per-expert exclusive prefix over chunks ----------------
__global__ __launch_bounds__(1024) void scan_kernel(const int* __restrict__ chunk_hist,
                                                    int* __restrict__ chunk_base,
                                                    int* __restrict__ cnt) {
  __shared__ int h[NCHUNK * E];  // 24 KB
  int t = threadIdx.x;
  for (int i = t; i < NCHUNK * E; i += 1024) h[i] = chunk_hist[i];
  __syncthreads();
  if (t < E) {
    int run = 0;
    for (int c = 0; c < NCHUNK; ++c) {
      int v = h[c * E + t];
      h[c * E + t] = run;
      run += v;
    }
    cnt[t] = run < CAP ? run : CAP;
  }
  __syncthreads();
  for (int i = t; i < NCHUNK * E; i += 1024) chunk_base[i] = h[i];
}

// ---------------- dispatch phase 3: placement + inverse slot map ----------------
__global__ __launch_bounds__(64) void place_kernel(const int* __restrict__ tidx,
                                                   const int* __restrict__ chunk_base,
                                                   int* __restrict__ token_list,
                                                   int* __restrict__ sid) {
  int c = blockIdx.x, lane = threadIdx.x;
  int idx = c * 64 + lane;
  int te = tidx[idx];
  unsigned long long mymask = 0;
  #pragma unroll
  for (int e = 0; e < E; ++e) {
    unsigned long long bal = __ballot(te == e);
    if (te == e) mymask = bal;
  }
  int rank = __popcll(mymask & ((1ull << lane) - 1ull));
  int pos = chunk_base[c * E + te] + rank;
  int s = -1;
  if (pos < CAP) {
    token_list[te * CAP + pos] = idx / K_TOP;
    s = te * CAP + pos;
  }
  sid[idx] = s;
}

// ---------------- fused gate+up GEMM -> S = silu(g)*u (bf16) ----------------
// A: bf16 rows (gathered or direct). B: fp32 [K=H rows][N cols] (native layout),
// staged coalesced + packed to bf16 in LDS. 128x64 tile, 4 waves 2x2.
__global__ __launch_bounds__(256) void gateup_kernel(
    const short* __restrict__ Xb, const float* __restrict__ Wg, const float* __restrict__ Wu,
    short* __restrict__ Sout, const int* __restrict__ tlist, const int* __restrict__ cnt_dev,
    int Nld, long long wstride, long long sstride) {
  int e = blockIdx.z;
  int cnt = cnt_dev ? cnt_dev[e] : T_TOK;
  int row0 = blockIdx.y * 128;
  if (row0 >= cnt) return;
  int col0 = blockIdx.x * 64;
  const float* wg = Wg + (long long)e * wstride;
  const float* wu = Wu + (long long)e * wstride;
  short* sbase = Sout + (long long)e * sstride;

  __shared__ __align__(16) short As[128 * 32];
  __shared__ __align__(16) short Bgs[64 * 32];
  __shared__ __align__(16) short Bus[64 * 32];

  int tid = threadIdx.x;
  int lane = tid & 63, wave = tid >> 6;

  // A staging (global_load_lds): row rr, 16B chunk ch
  int rr = tid >> 2, ch = tid & 3;
  int ra0 = row0 + rr, ra1 = ra0 + 64;
  if (tlist) {
    const int* tl = tlist + e * CAP;
    ra0 = tl[min(ra0, cnt - 1)];
    ra1 = tl[min(ra1, cnt - 1)];
  }
  const short* pa0 = Xb + (size_t)ra0 * H + ch * 8;
  const short* pa1 = Xb + (size_t)ra1 * H + ch * 8;
  short* ldsA0 = &As[(wave * 16) * 32];
  short* ldsA1 = &As[(64 + wave * 16) * 32];

  // B staging: n = lane (coalesced), k-octet = wave*8
  int bn = lane, kb = wave * 8;
  const float* pg = wg + (size_t)kb * Nld + col0 + bn;
  const float* pu = wu + (size_t)kb * Nld + col0 + bn;
  short* ldsBg = &Bgs[bn * 32 + kb];
  short* ldsBu = &Bus[bn * 32 + kb];

  int wm = wave & 1, wn = wave >> 1;
  int c = lane & 15, q = lane >> 4;
  const short* fA = &As[(wm * 64 + c) * 32 + q * 8];
  const short* fBg = &Bgs[(wn * 32 + c) * 32 + q * 8];
  const short* fBu = &Bus[(wn * 32 + c) * 32 + q * 8];

  f32x4 accg[4][2], accu[4][2];
  #pragma unroll
  for (int i = 0; i < 4; ++i)
    #pragma unroll
    for (int j = 0; j < 2; ++j) {
      accg[i][j] = (f32x4){0.f, 0.f, 0.f, 0.f};
      accu[i][j] = (f32x4){0.f, 0.f, 0.f, 0.f};
    }

  for (int k0 = 0; k0 < H; k0 += 32) {
    float gv[8], uv[8];
    const float* pgk = pg + (size_t)k0 * Nld;
    const float* puk = pu + (size_t)k0 * Nld;
    #pragma unroll
    for (int j = 0; j < 8; ++j) {
      gv[j] = pgk[(size_t)j * Nld];
      uv[j] = puk[(size_t)j * Nld];
    }
    __syncthreads();
    gload_lds16(pa0 + k0, ldsA0);
    gload_lds16(pa1 + k0, ldsA1);
    uint4 wvg, wvu;
    wvg.x = packbf2(gv[0], gv[1]); wvg.y = packbf2(gv[2], gv[3]);
    wvg.z = packbf2(gv[4], gv[5]); wvg.w = packbf2(gv[6], gv[7]);
    wvu.x = packbf2(uv[0], uv[1]); wvu.y = packbf2(uv[2], uv[3]);
    wvu.z = packbf2(uv[4], uv[5]); wvu.w = packbf2(uv[6], uv[7]);
    *(uint4*)ldsBg = wvg;
    *(uint4*)ldsBu = wvu;
    __syncthreads();
    short8v a[4], bg[2], bu[2];
    #pragma unroll
    for (int mi = 0; mi < 4; ++mi) a[mi] = *(const short8v*)(fA + mi * 16 * 32);
    #pragma unroll
    for (int ni = 0; ni < 2; ++ni) {
      bg[ni] = *(const short8v*)(fBg + ni * 16 * 32);
      bu[ni] = *(const short8v*)(fBu + ni * 16 * 32);
    }
    #pragma unroll
    for (int mi = 0; mi < 4; ++mi)
      #pragma unroll
      for (int ni = 0; ni < 2; ++ni) {
        accg[mi][ni] = __builtin_amdgcn_mfma_f32_16x16x32_bf16(a[mi], bg[ni], accg[mi][ni], 0, 0, 0);
        accu[mi][ni] = __builtin_amdgcn_mfma_f32_16x16x32_bf16(a[mi], bu[ni], accu[mi][ni], 0, 0, 0);
      }
  }
  #pragma unroll
  for (int mi = 0; mi < 4; ++mi) {
    int rbase = row0 + wm * 64 + mi * 16 + q * 4;
    #pragma unroll
    for (int ni = 0; ni < 2; ++ni) {
      int col = col0 + wn * 32 + ni * 16 + c;
      #pragma unroll
      for (int r = 0; r < 4; ++r) {
        float g = accg[mi][ni][r], u = accu[mi][ni][r];
        float s = (g / (1.f + __expf(-g))) * u;
        sbase[(size_t)(rbase + r) * Nld + col] = (short)f2bfbits(s);
      }
    }
  }
}

// ---------------- down GEMM: Y = S @ Wd (fp32 [K][H] native); store bf16 slots or fp32 rows ----
__global__ __launch_bounds__(256) void down_kernel(
    const short* __restrict__ Sin, const float* __restrict__ Wd,
    float* __restrict__ outF, short* __restrict__ outY,
    const int* __restrict__ cnt_dev, int Kdim, long long wstride, long long sstride) {
  int e = blockIdx.z;
  int cnt = cnt_dev ? cnt_dev[e] : T_TOK;
  int row0 = blockIdx.y * 128;
  if (row0 >= cnt) return;
  int col0 = blockIdx.x * 128;
  const short* sb = Sin + (long long)e * sstride;
  const float* wd = Wd + (long long)e * wstride;

  __shared__ __align__(16) short As[128 * 32];
  __shared__ __align__(16) short Bs[128 * 32];

  int tid = threadIdx.x;
  int lane = tid & 63, wave = tid >> 6;
  int rr = tid >> 2, ch = tid & 3;

  const short* pa0 = sb + (size_t)(row0 + rr) * Kdim + ch * 8;
  const short* pa1 = pa0 + (size_t)64 * Kdim;
  short* ldsA0 = &As[(wave * 16) * 32];
  short* ldsA1 = &As[(64 + wave * 16) * 32];

  // B staging: n = tid&127 (coalesced per wave), k-16-group = tid>>7
  int bn = tid & 127, kb = (tid >> 7) * 16;
  const float* pb = wd + (size_t)kb * H + col0 + bn;
  short* ldsB = &Bs[bn * 32 + kb];

  int wm = wave & 1, wn = wave >> 1;
  int c = lane & 15, q = lane >> 4;
  const short* fA = &As[(wm * 64 + c) * 32 + q * 8];
  const short* fB = &Bs[(wn * 64 + c) * 32 + q * 8];

  f32x4 acc[4][4];
  #pragma unroll
  for (int i = 0; i < 4; ++i)
    #pragma unroll
    for (int j = 0; j < 4; ++j) acc[i][j] = (f32x4){0.f, 0.f, 0.f, 0.f};

  for (int k0 = 0; k0 < Kdim; k0 += 32) {
    float bv[16];
    const float* pbk = pb + (size_t)k0 * H;
    #pragma unroll
    for (int j = 0; j < 16; ++j) bv[j] = pbk[(size_t)j * H];
    __syncthreads();
    gload_lds16(pa0 + k0, ldsA0);
    gload_lds16(pa1 + k0, ldsA1);
    uint4 w0, w1;
    w0.x = packbf2(bv[0], bv[1]);  w0.y = packbf2(bv[2], bv[3]);
    w0.z = packbf2(bv[4], bv[5]);  w0.w = packbf2(bv[6], bv[7]);
    w1.x = packbf2(bv[8], bv[9]);  w1.y = packbf2(bv[10], bv[11]);
    w1.z = packbf2(bv[12], bv[13]); w1.w = packbf2(bv[14], bv[15]);
    *(uint4*)ldsB = w0;
    *(uint4*)(ldsB + 8) = w1;
    __syncthreads();
    short8v a[4], b[4];
    #pragma unroll
    for (int mi = 0; mi < 4; ++mi) a[mi] = *(const short8v*)(fA + mi * 16 * 32);
    #pragma unroll
    for (int ni = 0; ni < 4; ++ni) b[ni] = *(const short8v*)(fB + ni * 16 * 32);
    #pragma unroll
    for (int mi = 0; mi < 4; ++mi)
      #pragma unroll
      for (int ni = 0; ni < 4; ++ni)
        acc[mi][ni] = __builtin_amdgcn_mfma_f32_16x16x32_bf16(a[mi], b[ni], acc[mi][ni], 0, 0, 0);
  }

  if (outY) {
    // routed: plain bf16 stores into slot buffer rows e*CAP + row
    #pragma unroll
    for (int mi = 0; mi < 4; ++mi) {
      int rb = row0 + wm * 64 + mi * 16 + q * 4;
      #pragma unroll
      for (int r = 0; r < 4; ++r) {
        short* yrow = outY + (size_t)(e * CAP + rb + r) * H;
        #pragma unroll
        for (int ni = 0; ni < 4; ++ni) {
          int col = col0 + wn * 64 + ni * 16 + c;
          yrow[col] = (short)f2bfbits(acc[mi][ni][r]);
        }
      }
    }
  } else {
    #pragma unroll
    for (int mi = 0; mi < 4; ++mi) {
      int rb = row0 + wm * 64 + mi * 16 + q * 4;
      #pragma unroll
      for (int ni = 0; ni < 4; ++ni) {
        int col = col0 + wn * 64 + ni * 16 + c;
        #pragma unroll
        for (int r = 0; r < 4; ++r)
          outF[(size_t)(rb + r) * H + col] = acc[mi][ni][r];
      }
    }
  }
}

// ---------------- combine: out[t] += sum_k w_k * Yr[sid_k] ----------------
__global__ __launch_bounds__(256) void combine_kernel(
    const short* __restrict__ Yr, const int* __restrict__ sid,
    const float* __restrict__ twt, float* __restrict__ out) {
  int t = blockIdx.x;
  int col = threadIdx.x * 4;
  float* op = out + (size_t)t * H + col;
  float4 o = *(float4*)op;
  #pragma unroll
  for (int k = 0; k < K_TOP; ++k) {
    int s = sid[t * K_TOP + k];
    if (s >= 0) {
      float w = twt[t * K_TOP + k];
      ushort4 y = *(const ushort4*)(Yr + (size_t)s * H + col);
      o.x += w * bf2f(y.x);
      o.y += w * bf2f(y.y);
      o.z += w * bf2f(y.z);
      o.w += w * bf2f(y.w);
    }
  }
  *(float4*)op = o;
}

extern "C" void kernel_launch(void* const* d_in, const int* in_sizes, int n_in,
                              void* d_out, int out_size, void* d_ws, size_t ws_size,
                              hipStream_t stream) {
  const float* x       = (const float*)d_in[0];
  const float* gate_w  = (const float*)d_in[1];
  const float* w_gate  = (const float*)d_in[2];
  const float* w_up    = (const float*)d_in[3];
  const float* w_down  = (const float*)d_in[4];
  const float* sw_gate = (const float*)d_in[5];
  const float* sw_up   = (const float*)d_in[6];
  const float* sw_down = (const float*)d_in[7];
  float* out = (float*)d_out;
  char* ws = (char*)d_ws;

  size_t o = 0;
  short* xb   = (short*)(ws + o); o += (size_t)T_TOK * H * 2;          // 4 MB
  short* Sr   = (short*)(ws + o); o += (size_t)E * CAP * I_DIM * 2;    // 33 MB
  short* Ss   = (short*)(ws + o); o += (size_t)T_TOK * IS_DIM * 2;     // 5.5 MB
  short* Yr   = (short*)(ws + o); o += (size_t)E * CAP * H * 2;        // 48 MB
  int*   tidx = (int*)(ws + o);   o += (size_t)T_TOK * K_TOP * 4;
  float* twt  = (float*)(ws + o); o += (size_t)T_TOK * K_TOP * 4;
  int*   sid  = (int*)(ws + o);   o += (size_t)T_TOK * K_TOP * 4;
  int*   tl   = (int*)(ws + o);   o += (size_t)E * CAP * 4;
  int*   cnt  = (int*)(ws + o);   o += 256;
  int*   chist = (int*)(ws + o);  o += (size_t)NCHUNK * E * 4;
  int*   cbase = (int*)(ws + o);  o += (size_t)NCHUNK * E * 4;

  cast_x_kernel<<<(T_TOK * H) / 1024, 256, 0, stream>>>(x, xb);
  gating_kernel<<<T_TOK, 64, 0, stream>>>(x, gate_w, tidx, twt);
  hist_kernel<<<NCHUNK, 64, 0, stream>>>(tidx, chist);
  scan_kernel<<<1, 1024, 0, stream>>>(chist, cbase, cnt);
  place_kernel<<<NCHUNK, 64, 0, stream>>>(tidx, cbase, tl, sid);

  // routed gate+up -> Sr (B = w_gate/w_up fp32, native [H][I] layout)
  gateup_kernel<<<dim3(I_DIM / 64, CAP / 128, E), 256, 0, stream>>>(
      xb, w_gate, w_up, Sr, tl, cnt, I_DIM, (long long)H * I_DIM, (long long)CAP * I_DIM);
  // shared gate+up -> Ss
  gateup_kernel<<<dim3(IS_DIM / 64, T_TOK / 128, 1), 256, 0, stream>>>(
      xb, sw_gate, sw_up, Ss, nullptr, nullptr, IS_DIM, 0, 0);
  // shared down: fp32 store, fully initializes out
  down_kernel<<<dim3(H / 128, T_TOK / 128, 1), 256, 0, stream>>>(
      Ss, sw_down, out, nullptr, nullptr, IS_DIM, 0, 0);
  // routed down: bf16 stores into slot buffer
  down_kernel<<<dim3(H / 128, CAP / 128, E), 256, 0, stream>>>(
      Sr, w_down, nullptr, Yr, cnt, I_DIM, (long long)I_DIM * H, (long long)CAP * I_DIM);
  // final combine
  combine_kernel<<<T_TOK, 256, 0, stream>>>(Yr, sid, twt, out);
}